// Round 1
// baseline (13.934 us; speedup 1.0000x reference)
//
#include <hip/hip_runtime.h>

// EquivariantUpSampling:
//  x: (8,128,32,32) f32, p: (8,3) int in {0,1}
//  out: (8,256,64,64) f32
//  out[b, cc*4 + f*2 + r, 2*i + p0, 2*j + p1] = rot_r(x[b, cc*2+f])[i, j]
//  where r = p[b,2], p0 = p[b,0], p1 = p[b,1], and rot_r is an exact
//  pixel-centered rot90 (derived from the tile/rotate/crop trick):
//    r=0: y[i,j]   r=1: y[j,(32-i)&31]   r=2: y[(32-i)&31,(32-j)&31]   r=3: y[(32-j)&31,i]
//  All other output elements are zero.

__global__ __launch_bounds__(256) void eqs_scatter_kernel(
    const float* __restrict__ x, const int* __restrict__ p,
    float* __restrict__ out) {
    const int tid = blockIdx.x * blockDim.x + threadIdx.x;   // one float4 per thread
    const int t  = tid << 2;                                 // element index
    const int b  = t >> 20;          // 256*64*64 = 2^20 elems per batch
    const int ch = (t >> 12) & 255;  // 64*64 = 2^12 elems per channel
    const int I  = (t >> 6) & 63;
    const int J0 = t & 63;           // multiple of 4

    const int p0 = p[b * 3 + 0];
    const int p1 = p[b * 3 + 1];
    const int r  = p[b * 3 + 2];

    float4 v = make_float4(0.f, 0.f, 0.f, 0.f);

    // Nonzero only when output row parity matches p0 and channel's s_H slot == r.
    if (((I & 1) == p0) && ((ch & 1) == r)) {
        const int i    = I >> 1;
        const int cc   = ch >> 2;
        const int f    = (ch >> 1) & 1;
        const int c_in = cc * 2 + f;
        const float* __restrict__ xb = x + ((b * 128 + c_in) << 10);  // 32*32 = 1024
        const int j0 = J0 >> 1;  // even; this float4 covers source cols j0, j0+1

        float s0, s1;
        if (r == 0) {
            s0 = xb[(i << 5) + j0];
            s1 = xb[(i << 5) + j0 + 1];
        } else {  // r == 1 (p values are {0,1}; r>=2 can't pass ch&1==r)
            const int col = (32 - i) & 31;
            s0 = xb[(j0 << 5) + col];
            s1 = xb[((j0 + 1) << 5) + col];
        }
        if (p1 == 0) { v.x = s0; v.z = s1; }
        else         { v.y = s0; v.w = s1; }
    }

    reinterpret_cast<float4*>(out)[tid] = v;
}

extern "C" void kernel_launch(void* const* d_in, const int* in_sizes, int n_in,
                              void* d_out, int out_size, void* d_ws, size_t ws_size,
                              hipStream_t stream) {
    const float* x = (const float*)d_in[0];
    const int*   p = (const int*)d_in[1];
    float* out = (float*)d_out;

    // out_size = 8*256*64*64 = 8388608 elements = 2097152 float4s
    const int n4 = out_size >> 2;
    const int block = 256;
    const int grid = (n4 + block - 1) / block;  // 8192
    eqs_scatter_kernel<<<grid, block, 0, stream>>>(x, p, out);
}

// Round 2
// 12.055 us; speedup vs baseline: 1.1559x; 1.1559x over previous
//
#include <hip/hip_runtime.h>

// EquivariantUpSampling:
//  x: (8,128,32,32) f32, p: (8,3) int in {0,1}
//  out: (8,256,64,64) f32
//  out[b, cc*4 + f*2 + r, 2*i + p0, 2*j + p1] = rot_r(x[b, cc*2+f])[i, j]
//  where r = p[b,2], p0 = p[b,0], p1 = p[b,1]; rot_r is exact pixel-centered rot90:
//    r=0: y[i,j]   r=1: y[j,(32-i)&31]   (r>=2 unreachable: p values are in {0,1})
//  All other output elements are zero.
//
// Layout: one block == one output channel (64x64 = 4096 f32 = 1024 float4).
// b = blk>>8 and ch = blk&255 are block-uniform -> p[] loads become s_load,
// and the (ch&1)!=r zero-channel case is a uniform branch-free store loop.

__global__ __launch_bounds__(256) void eqs_scatter_kernel(
    const float* __restrict__ x, const int* __restrict__ p,
    float4* __restrict__ out) {
    const int blk = blockIdx.x;        // 2048 blocks
    const int b   = blk >> 8;          // 256 channels per batch
    const int ch  = blk & 255;
    const int r   = p[b * 3 + 2];      // block-uniform -> scalar load

    float4* __restrict__ ob = out + (blk << 10);   // 1024 float4 per channel
    const int tid = threadIdx.x;

    if ((ch & 1) != r) {               // uniform: whole channel is zero
        const float4 z = make_float4(0.f, 0.f, 0.f, 0.f);
        ob[tid]       = z;
        ob[tid + 256] = z;
        ob[tid + 512] = z;
        ob[tid + 768] = z;
        return;
    }

    const int p0 = p[b * 3 + 0];
    const int p1 = p[b * 3 + 1];
    const int cc = ch >> 2;
    const int f  = (ch >> 1) & 1;
    const float* __restrict__ xb = x + ((b * 128 + cc * 2 + f) << 10); // 32*32

    const int j0    = (tid & 15) << 1; // source col pair: output cols (tid&15)*4 .. +3
    const int rowhi = tid >> 4;        // 0..15

    #pragma unroll
    for (int it = 0; it < 4; ++it) {
        const int I = (it << 4) + rowhi;           // output row 0..63
        float4 v = make_float4(0.f, 0.f, 0.f, 0.f);
        if ((I & 1) == p0) {                       // row parity matches scatter slot
            const int i = I >> 1;
            float s0, s1;
            if (r == 0) {
                s0 = xb[(i << 5) + j0];
                s1 = xb[(i << 5) + j0 + 1];
            } else {                               // r == 1
                const int col = (32 - i) & 31;
                s0 = xb[(j0 << 5) + col];
                s1 = xb[((j0 + 1) << 5) + col];
            }
            if (p1 == 0) { v.x = s0; v.z = s1; }
            else         { v.y = s0; v.w = s1; }
        }
        ob[(it << 8) + tid] = v;
    }
}

extern "C" void kernel_launch(void* const* d_in, const int* in_sizes, int n_in,
                              void* d_out, int out_size, void* d_ws, size_t ws_size,
                              hipStream_t stream) {
    const float* x = (const float*)d_in[0];
    const int*   p = (const int*)d_in[1];
    float4* out = (float4*)d_out;

    // out_size = 8*256*64*64 = 8388608 elems -> 2048 blocks of one channel each
    const int grid = out_size >> 12;   // 4096 elems per block
    eqs_scatter_kernel<<<grid, 256, 0, stream>>>(x, p, out);
}

// Round 3
// 11.957 us; speedup vs baseline: 1.1654x; 1.0082x over previous
//
#include <hip/hip_runtime.h>

// EquivariantUpSampling:
//  x: (8,128,32,32) f32, p: (8,3) int in {0,1}
//  out: (8,256,64,64) f32
//  out[b, cc*4 + f*2 + r, 2*i + p0, 2*j + p1] = rot_r(x[b, cc*2+f])[i, j]
//  where r = p[b,2], p0 = p[b,0], p1 = p[b,1]; rot_r is exact pixel-centered rot90:
//    r=0: y[i,j]   r=1: y[j,(32-i)&31]   (r>=2 unreachable: p values are in {0,1})
//  All other output elements are zero.
//
// One block == one output channel (64x64 f32 = 1024 float4). b, ch are
// block-uniform -> p[] loads are scalar; zero channels take a uniform
// pure-fill path. Gather channels: each thread owns a ROW PAIR (2q, 2q+1)
// in a 4-column window -> exactly one row carries data (2q+p0, uniform
// offset), the other is zeros. No per-lane branches at all.

__global__ __launch_bounds__(256) void eqs_scatter_kernel(
    const float* __restrict__ x, const int* __restrict__ p,
    float4* __restrict__ out) {
    const int blk = blockIdx.x;        // 2048 blocks
    const int b   = blk >> 8;
    const int ch  = blk & 255;
    const int r   = p[b * 3 + 2];      // uniform -> s_load

    float4* __restrict__ ob = out + (blk << 10);   // 1024 float4 per channel
    const int tid = threadIdx.x;
    const float4 z = make_float4(0.f, 0.f, 0.f, 0.f);

    if ((ch & 1) != r) {               // uniform: whole channel is zero
        ob[tid]       = z;
        ob[tid + 256] = z;
        ob[tid + 512] = z;
        ob[tid + 768] = z;
        return;
    }

    const int p0 = p[b * 3 + 0];
    const int p1 = p[b * 3 + 1];
    const float* __restrict__ xb =
        x + ((b * 128 + (ch >> 2) * 2 + ((ch >> 1) & 1)) << 10);  // 32*32

    const int jj = tid & 15;           // float4 column 0..15 (output cols 4*jj..4*jj+3)
    const int j0 = jj << 1;            // source cols j0, j0+1
    const int q0 = tid >> 4;           // row-pair index 0..15; +16 on 2nd iter
    const int sA = p0 << 4;            // uniform: float4-row offset of the data row
    const int sB = (1 - p0) << 4;      // uniform: the zero row of the pair

    #pragma unroll
    for (int it = 0; it < 2; ++it) {
        const int q = q0 + (it << 4);  // source row i = q (0..31)
        float s0, s1;
        if (r == 0) {                  // uniform branch
            s0 = xb[(q << 5) + j0];
            s1 = xb[(q << 5) + j0 + 1];
        } else {                       // r == 1
            const int col = (32 - q) & 31;
            s0 = xb[(j0 << 5) + col];
            s1 = xb[((j0 + 1) << 5) + col];
        }
        float4 v = z;
        if (p1 == 0) { v.x = s0; v.z = s1; }   // uniform branch
        else         { v.y = s0; v.w = s1; }
        const int base = (q << 5) + jj;        // float4 index of row 2q, col jj
        ob[base + sA] = v;                     // data row 2q+p0
        ob[base + sB] = z;                     // zero row 2q+1-p0
    }
}

extern "C" void kernel_launch(void* const* d_in, const int* in_sizes, int n_in,
                              void* d_out, int out_size, void* d_ws, size_t ws_size,
                              hipStream_t stream) {
    const float* x = (const float*)d_in[0];
    const int*   p = (const int*)d_in[1];
    float4* out = (float4*)d_out;

    const int grid = out_size >> 12;   // one 4096-elem channel per block = 2048
    eqs_scatter_kernel<<<grid, 256, 0, stream>>>(x, p, out);
}